// Round 1
// baseline (1484.889 us; speedup 1.0000x reference)
//
#include <hip/hip_runtime.h>
#include <hip/hip_bf16.h>

#define DIN 256
#define DHID 128
#define NCLS 47

// --- degree / norm ---------------------------------------------------------
__global__ void k_init_deg(float* deg, int n) {
    int i = blockIdx.x * blockDim.x + threadIdx.x;
    if (i < n) deg[i] = 1.0f;  // self-loop
}

__global__ void k_deg(const int* __restrict__ dst, float* deg, int E) {
    int e = blockIdx.x * blockDim.x + threadIdx.x;
    if (e < E) atomicAdd(&deg[dst[e]], 1.0f);
}

__global__ void k_dinv(float* deg, int n) {
    int i = blockIdx.x * blockDim.x + threadIdx.x;
    if (i < n) deg[i] = 1.0f / sqrtf(deg[i]);  // deg >= 1 always
}

// --- GEMM1: h[n,128] = x[n,256] @ W1[256,128] ------------------------------
// Block = 128 threads, 4 rows per block. x rows staged in LDS (broadcast
// reads), W1 column-coalesced from L2 (128 KB, L2-resident), 4 FMA per load.
__global__ void k_gemm1(const float* __restrict__ x, const float* __restrict__ W1,
                        float* __restrict__ h, int n) {
    __shared__ float xs[4][DIN];
    int row0 = blockIdx.x * 4;
    int t = threadIdx.x;
    for (int i = t; i < 4 * DIN; i += 128) {
        int r = i / DIN, c = i % DIN;
        int row = row0 + r;
        xs[r][c] = (row < n) ? x[(long long)row * DIN + c] : 0.0f;
    }
    __syncthreads();
    float acc0 = 0.f, acc1 = 0.f, acc2 = 0.f, acc3 = 0.f;
    #pragma unroll 8
    for (int k = 0; k < DIN; ++k) {
        float w = W1[k * DHID + t];
        acc0 += xs[0][k] * w;
        acc1 += xs[1][k] * w;
        acc2 += xs[2][k] * w;
        acc3 += xs[3][k] * w;
    }
    float acc[4] = {acc0, acc1, acc2, acc3};
    for (int r = 0; r < 4; ++r) {
        int row = row0 + r;
        if (row < n) h[(long long)row * DHID + t] = acc[r];
    }
}

// --- edge scatter, layer 1: agg1[dst] += h[src] * norm ---------------------
__global__ void k_scatter1(const int* __restrict__ src, const int* __restrict__ dst,
                           const float* __restrict__ dinv, const float* __restrict__ h,
                           float* agg1, int E) {
    long long gid = (long long)blockIdx.x * blockDim.x + threadIdx.x;
    int e = (int)(gid >> 7);
    int t = (int)(gid & 127);
    if (e < E) {
        int s = src[e], d = dst[e];
        float nrm = dinv[s] * dinv[d];
        atomicAdd(&agg1[(long long)d * DHID + t], h[(long long)s * DHID + t] * nrm);
    }
}

// --- fused self-loop + bias + relu: h1 = relu(agg1 + h*dinv^2 + b1) --------
__global__ void k_fuse1(float* agg1, const float* __restrict__ h,
                        const float* __restrict__ dinv, const float* __restrict__ b1,
                        int n) {
    long long idx = (long long)blockIdx.x * blockDim.x + threadIdx.x;
    if (idx < (long long)n * DHID) {
        int i = (int)(idx >> 7);
        int t = (int)(idx & 127);
        float di = dinv[i];
        float v = agg1[idx] + h[idx] * di * di + b1[t];
        agg1[idx] = v > 0.f ? v : 0.f;  // in place -> h1
    }
}

// --- GEMM2: h2[n,47] = h1[n,128] @ W2[128,47] ------------------------------
__global__ void k_gemm2(const float* __restrict__ h1, const float* __restrict__ W2,
                        float* __restrict__ h2, int n) {
    __shared__ float hs[4][DHID];
    int row0 = blockIdx.x * 4;
    int t = threadIdx.x;  // 0..63
    for (int i = t; i < 4 * DHID; i += 64) {
        int r = i / DHID, c = i % DHID;
        int row = row0 + r;
        hs[r][c] = (row < n) ? h1[(long long)row * DHID + c] : 0.0f;
    }
    __syncthreads();
    if (t < NCLS) {
        float acc0 = 0.f, acc1 = 0.f, acc2 = 0.f, acc3 = 0.f;
        #pragma unroll 8
        for (int k = 0; k < DHID; ++k) {
            float w = W2[k * NCLS + t];
            acc0 += hs[0][k] * w;
            acc1 += hs[1][k] * w;
            acc2 += hs[2][k] * w;
            acc3 += hs[3][k] * w;
        }
        float acc[4] = {acc0, acc1, acc2, acc3};
        for (int r = 0; r < 4; ++r) {
            int row = row0 + r;
            if (row < n) h2[(long long)row * NCLS + t] = acc[r];
        }
    }
}

// --- init out with bias + self-loop: out = b2 + h2*dinv^2 ------------------
__global__ void k_init_out(float* out, const float* __restrict__ h2,
                           const float* __restrict__ dinv, const float* __restrict__ b2,
                           int n) {
    long long idx = (long long)blockIdx.x * blockDim.x + threadIdx.x;
    if (idx < (long long)n * NCLS) {
        int i = (int)(idx / NCLS);
        int j = (int)(idx - (long long)i * NCLS);
        float di = dinv[i];
        out[idx] = b2[j] + h2[idx] * di * di;
    }
}

// --- edge scatter, layer 2: out[dst] += h2[src] * norm ---------------------
__global__ void k_scatter2(const int* __restrict__ src, const int* __restrict__ dst,
                           const float* __restrict__ dinv, const float* __restrict__ h2,
                           float* out, int E) {
    long long gid = (long long)blockIdx.x * blockDim.x + threadIdx.x;
    int e = (int)(gid >> 6);
    int t = (int)(gid & 63);
    if (e < E && t < NCLS) {
        int s = src[e], d = dst[e];
        float nrm = dinv[s] * dinv[d];
        atomicAdd(&out[(long long)d * NCLS + t], h2[(long long)s * NCLS + t] * nrm);
    }
}

extern "C" void kernel_launch(void* const* d_in, const int* in_sizes, int n_in,
                              void* d_out, int out_size, void* d_ws, size_t ws_size,
                              hipStream_t stream) {
    const float* x  = (const float*)d_in[0];
    const int*   ei = (const int*)d_in[1];   // [2, E] flat, int32
    const float* W1 = (const float*)d_in[2];
    const float* b1 = (const float*)d_in[3];
    const float* W2 = (const float*)d_in[4];
    const float* b2 = (const float*)d_in[5];

    const int n = in_sizes[0] / DIN;       // 100000
    const int E = in_sizes[1] / 2;         // 1600000
    const int* src = ei;
    const int* dst = ei + E;

    float* out = (float*)d_out;

    // workspace layout (floats): [deg/dinv n][h n*128][agg1/h1 n*128][h2 n*47]
    float* ws   = (float*)d_ws;
    float* dinv = ws;                       // deg, overwritten by dinv
    float* h    = ws + 131072;              // aligned past n
    float* agg1 = h + (long long)n * DHID;  // becomes h1 in place
    float* h2   = agg1 + (long long)n * DHID;

    // 1. degree + norm
    k_init_deg<<<(n + 255) / 256, 256, 0, stream>>>(dinv, n);
    k_deg<<<(E + 255) / 256, 256, 0, stream>>>(dst, dinv, E);
    k_dinv<<<(n + 255) / 256, 256, 0, stream>>>(dinv, n);

    // 2. layer 1
    k_gemm1<<<(n + 3) / 4, 128, 0, stream>>>(x, W1, h, n);
    hipMemsetAsync(agg1, 0, (size_t)n * DHID * sizeof(float), stream);
    {
        long long total = (long long)E * DHID;
        k_scatter1<<<(unsigned)((total + 255) / 256), 256, 0, stream>>>(src, dst, dinv, h, agg1, E);
    }
    k_fuse1<<<(unsigned)(((long long)n * DHID + 255) / 256), 256, 0, stream>>>(agg1, h, dinv, b1, n);

    // 3. layer 2
    k_gemm2<<<(n + 3) / 4, 64, 0, stream>>>(agg1, W2, h2, n);
    k_init_out<<<(unsigned)(((long long)n * NCLS + 255) / 256), 256, 0, stream>>>(out, h2, dinv, b2, n);
    {
        long long total = (long long)E * 64;
        k_scatter2<<<(unsigned)((total + 255) / 256), 256, 0, stream>>>(src, dst, dinv, h2, out, E);
    }
}

// Round 2
// 867.327 us; speedup vs baseline: 1.7120x; 1.7120x over previous
//
#include <hip/hip_runtime.h>
#include <hip/hip_bf16.h>

#define DIN 256
#define DHID 128
#define NCLS 47
#define SCAN_CHUNK 1024

// ============================ CSR build ====================================
__global__ void k_count(const int* __restrict__ dst, int* degi, int E) {
    int e = blockIdx.x * blockDim.x + threadIdx.x;
    if (e < E) atomicAdd(&degi[dst[e]], 1);
}

__global__ void k_dinv(const int* __restrict__ degi, float* dinv, int n) {
    int i = blockIdx.x * blockDim.x + threadIdx.x;
    if (i < n) dinv[i] = rsqrtf((float)(degi[i] + 1));  // +1 self-loop
}

// exclusive scan of degi -> fill (begin offsets), 1024 elems/block
__global__ void k_scan1(const int* __restrict__ degi, int* __restrict__ fill,
                        int* __restrict__ bsum, int n) {
    __shared__ int wsum[4];
    int b = blockIdx.x, t = threadIdx.x;
    int base = b * SCAN_CHUNK + t * 4;
    int v0 = (base + 0 < n) ? degi[base + 0] : 0;
    int v1 = (base + 1 < n) ? degi[base + 1] : 0;
    int v2 = (base + 2 < n) ? degi[base + 2] : 0;
    int v3 = (base + 3 < n) ? degi[base + 3] : 0;
    int s = v0 + v1 + v2 + v3;
    int lane = t & 63, w = t >> 6;
    int sc = s;
    for (int off = 1; off < 64; off <<= 1) {
        int u = __shfl_up(sc, off, 64);
        if (lane >= off) sc += u;
    }
    if (lane == 63) wsum[w] = sc;
    __syncthreads();
    int wadd = 0;
    for (int i = 0; i < w; ++i) wadd += wsum[i];
    int excl = wadd + sc - s;  // exclusive prefix for this thread's 4 elems
    if (base + 0 < n) fill[base + 0] = excl;
    if (base + 1 < n) fill[base + 1] = excl + v0;
    if (base + 2 < n) fill[base + 2] = excl + v0 + v1;
    if (base + 3 < n) fill[base + 3] = excl + v0 + v1 + v2;
    if (t == 255) bsum[b] = excl + s;  // block total
}

__global__ void k_scan2(int* bsum, int B) {
    if (blockIdx.x == 0 && threadIdx.x == 0) {
        int run = 0;
        for (int i = 0; i < B; ++i) { int v = bsum[i]; bsum[i] = run; run += v; }
    }
}

__global__ void k_scan3(int* fill, const int* __restrict__ bsum, int n) {
    int b = blockIdx.x, t = threadIdx.x;
    int add = bsum[b];
    int base = b * SCAN_CHUNK + t * 4;
    for (int i = 0; i < 4; ++i)
        if (base + i < n) fill[base + i] += add;
}

// scatter edges into dst-sorted order; fill[] advances from begin to end offsets
__global__ void k_fill(const int* __restrict__ src, const int* __restrict__ dst,
                       int* fill, int* __restrict__ ssrc, int E) {
    int e = blockIdx.x * blockDim.x + threadIdx.x;
    if (e < E) {
        int d = dst[e];
        int pos = atomicAdd(&fill[d], 1);
        ssrc[pos] = src[e];
    }
}

// ============================ GEMM1 ========================================
// h[n,128] = x[n,256] @ W1[256,128]; 4 rows/block, x rows in LDS.
__global__ void k_gemm1(const float* __restrict__ x, const float* __restrict__ W1,
                        float* __restrict__ h, int n) {
    __shared__ float xs[4][DIN];
    int row0 = blockIdx.x * 4;
    int t = threadIdx.x;
    for (int i = t; i < 4 * DIN; i += 128) {
        int r = i / DIN, c = i % DIN;
        int row = row0 + r;
        xs[r][c] = (row < n) ? x[(long long)row * DIN + c] : 0.0f;
    }
    __syncthreads();
    float acc0 = 0.f, acc1 = 0.f, acc2 = 0.f, acc3 = 0.f;
    #pragma unroll 8
    for (int k = 0; k < DIN; ++k) {
        float w = W1[k * DHID + t];
        acc0 += xs[0][k] * w;
        acc1 += xs[1][k] * w;
        acc2 += xs[2][k] * w;
        acc3 += xs[3][k] * w;
    }
    float acc[4] = {acc0, acc1, acc2, acc3};
    for (int r = 0; r < 4; ++r) {
        int row = row0 + r;
        if (row < n) h[(long long)row * DHID + t] = acc[r];
    }
}

// ===================== gather layer 1 (fused epilogue) =====================
// one wave (64 lanes) per dst node, float2 per lane; h1 = relu(agg + self + b1)
__global__ void k_gather1(const int* __restrict__ fillend, const int* __restrict__ degi,
                          const int* __restrict__ ssrc, const float* __restrict__ dinv,
                          const float* __restrict__ h, const float* __restrict__ b1,
                          float* __restrict__ h1, int n) {
    int node = blockIdx.x * 4 + (threadIdx.x >> 6);
    int t = threadIdx.x & 63;
    if (node >= n) return;
    int cnt = degi[node];
    int beg = fillend[node] - cnt;
    const float2* hp = (const float2*)h;   // row stride 64 float2
    float ax = 0.f, ay = 0.f;
    for (int k = 0; k < cnt; ++k) {
        int s = ssrc[beg + k];
        float ds = dinv[s];
        float2 hv = hp[(long long)s * 64 + t];
        ax += ds * hv.x;
        ay += ds * hv.y;
    }
    float di = dinv[node];
    float2 hs = hp[(long long)node * 64 + t];
    float2 bb = ((const float2*)b1)[t];
    float vx = di * ax + hs.x * di * di + bb.x;
    float vy = di * ay + hs.y * di * di + bb.y;
    float2 o;
    o.x = vx > 0.f ? vx : 0.f;
    o.y = vy > 0.f ? vy : 0.f;
    ((float2*)h1)[(long long)node * 64 + t] = o;
}

// ============================ GEMM2 ========================================
__global__ void k_gemm2(const float* __restrict__ h1, const float* __restrict__ W2,
                        float* __restrict__ h2, int n) {
    __shared__ float hs[4][DHID];
    int row0 = blockIdx.x * 4;
    int t = threadIdx.x;  // 0..63
    for (int i = t; i < 4 * DHID; i += 64) {
        int r = i / DHID, c = i % DHID;
        int row = row0 + r;
        hs[r][c] = (row < n) ? h1[(long long)row * DHID + c] : 0.0f;
    }
    __syncthreads();
    if (t < NCLS) {
        float acc0 = 0.f, acc1 = 0.f, acc2 = 0.f, acc3 = 0.f;
        #pragma unroll 8
        for (int k = 0; k < DHID; ++k) {
            float w = W2[k * NCLS + t];
            acc0 += hs[0][k] * w;
            acc1 += hs[1][k] * w;
            acc2 += hs[2][k] * w;
            acc3 += hs[3][k] * w;
        }
        float acc[4] = {acc0, acc1, acc2, acc3};
        for (int r = 0; r < 4; ++r) {
            int row = row0 + r;
            if (row < n) h2[(long long)row * NCLS + t] = acc[r];
        }
    }
}

// ===================== gather layer 2 (fused epilogue) =====================
// one wave per dst node, lanes 0..46 carry features; out = agg + self + b2
__global__ void k_gather2(const int* __restrict__ fillend, const int* __restrict__ degi,
                          const int* __restrict__ ssrc, const float* __restrict__ dinv,
                          const float* __restrict__ h2, const float* __restrict__ b2,
                          float* __restrict__ out, int n) {
    int node = blockIdx.x * 4 + (threadIdx.x >> 6);
    int t = threadIdx.x & 63;
    if (node >= n) return;
    int cnt = degi[node];
    int beg = fillend[node] - cnt;
    float acc = 0.f;
    bool act = (t < NCLS);
    for (int k = 0; k < cnt; ++k) {
        int s = ssrc[beg + k];
        float ds = dinv[s];
        if (act) acc += ds * h2[(long long)s * NCLS + t];
    }
    if (act) {
        float di = dinv[node];
        float v = di * acc + h2[(long long)node * NCLS + t] * di * di + b2[t];
        out[(long long)node * NCLS + t] = v;
    }
}

// ===========================================================================
extern "C" void kernel_launch(void* const* d_in, const int* in_sizes, int n_in,
                              void* d_out, int out_size, void* d_ws, size_t ws_size,
                              hipStream_t stream) {
    const float* x  = (const float*)d_in[0];
    const int*   ei = (const int*)d_in[1];
    const float* W1 = (const float*)d_in[2];
    const float* b1 = (const float*)d_in[3];
    const float* W2 = (const float*)d_in[4];
    const float* b2 = (const float*)d_in[5];

    const int n = in_sizes[0] / DIN;   // 100000
    const int E = in_sizes[1] / 2;     // 1600000
    const int* src = ei;
    const int* dst = ei + E;
    float* out = (float*)d_out;

    // workspace layout (4-byte elems), ~110 MB total
    char* w = (char*)d_ws;
    int*   degi = (int*)w;                     w += (size_t)n * 4;        // in-deg (no self)
    int*   fill = (int*)w;                     w += (size_t)n * 4;        // scan -> end ptrs
    int*   bsum = (int*)w;                     w += 128 * 4;
    float* dinv = (float*)w;                   w += (size_t)n * 4;
    int*   ssrc = (int*)w;                     w += (size_t)E * 4;        // dst-sorted src
    float* h    = (float*)w;                   w += (size_t)n * DHID * 4; // x@W1
    float* h1   = (float*)w;                   w += (size_t)n * DHID * 4; // relu(...)
    float* h2   = h;                           // alias: h dead after gather1

    const int B = (n + SCAN_CHUNK - 1) / SCAN_CHUNK;  // 98

    // 1. CSR build + norms
    hipMemsetAsync(degi, 0, (size_t)n * sizeof(int), stream);
    k_count<<<(E + 255) / 256, 256, 0, stream>>>(dst, degi, E);
    k_dinv<<<(n + 255) / 256, 256, 0, stream>>>(degi, dinv, n);
    k_scan1<<<B, 256, 0, stream>>>(degi, fill, bsum, n);
    k_scan2<<<1, 64, 0, stream>>>(bsum, B);
    k_scan3<<<B, 256, 0, stream>>>(fill, bsum, n);
    k_fill<<<(E + 255) / 256, 256, 0, stream>>>(src, dst, fill, ssrc, E);

    // 2. layer 1: transform then gather-aggregate (fused bias+self+relu)
    k_gemm1<<<(n + 3) / 4, 128, 0, stream>>>(x, W1, h, n);
    k_gather1<<<(n + 3) / 4, 256, 0, stream>>>(fill, degi, ssrc, dinv, h, b1, h1, n);

    // 3. layer 2: transform then gather-aggregate (fused bias+self)
    k_gemm2<<<(n + 3) / 4, 64, 0, stream>>>(h1, W2, h2, n);
    k_gather2<<<(n + 3) / 4, 256, 0, stream>>>(fill, degi, ssrc, dinv, h2, b2, out, n);
}

// Round 3
// 739.349 us; speedup vs baseline: 2.0084x; 1.1731x over previous
//
#include <hip/hip_runtime.h>
#include <hip/hip_bf16.h>

#define DIN 256
#define DHID 128
#define NCLS 47
#define SCAN_CHUNK 1024

typedef __attribute__((ext_vector_type(8))) short short8;   // 8 bf16 (4 VGPRs)
typedef __attribute__((ext_vector_type(4))) float f32x4;

__device__ __forceinline__ short f2bf(float f) {
    __bf16 b = (__bf16)f;                 // RNE convert
    return __builtin_bit_cast(short, b);
}

// ============================ CSR build ====================================
__global__ void k_count(const int* __restrict__ dst, int* degi, int E) {
    int e = blockIdx.x * blockDim.x + threadIdx.x;
    if (e < E) atomicAdd(&degi[dst[e]], 1);
}

__global__ void k_dinv(const int* __restrict__ degi, float* dinv, int n) {
    int i = blockIdx.x * blockDim.x + threadIdx.x;
    if (i < n) dinv[i] = rsqrtf((float)(degi[i] + 1));  // +1 self-loop
}

__global__ void k_scan1(const int* __restrict__ degi, int* __restrict__ fill,
                        int* __restrict__ bsum, int n) {
    __shared__ int wsum[4];
    int b = blockIdx.x, t = threadIdx.x;
    int base = b * SCAN_CHUNK + t * 4;
    int v0 = (base + 0 < n) ? degi[base + 0] : 0;
    int v1 = (base + 1 < n) ? degi[base + 1] : 0;
    int v2 = (base + 2 < n) ? degi[base + 2] : 0;
    int v3 = (base + 3 < n) ? degi[base + 3] : 0;
    int s = v0 + v1 + v2 + v3;
    int lane = t & 63, w = t >> 6;
    int sc = s;
    for (int off = 1; off < 64; off <<= 1) {
        int u = __shfl_up(sc, off, 64);
        if (lane >= off) sc += u;
    }
    if (lane == 63) wsum[w] = sc;
    __syncthreads();
    int wadd = 0;
    for (int i = 0; i < w; ++i) wadd += wsum[i];
    int excl = wadd + sc - s;
    if (base + 0 < n) fill[base + 0] = excl;
    if (base + 1 < n) fill[base + 1] = excl + v0;
    if (base + 2 < n) fill[base + 2] = excl + v0 + v1;
    if (base + 3 < n) fill[base + 3] = excl + v0 + v1 + v2;
    if (t == 255) bsum[b] = excl + s;
}

__global__ void k_scan2(int* bsum, int B) {
    if (blockIdx.x == 0 && threadIdx.x == 0) {
        int run = 0;
        for (int i = 0; i < B; ++i) { int v = bsum[i]; bsum[i] = run; run += v; }
    }
}

__global__ void k_scan3(int* fill, const int* __restrict__ bsum, int n) {
    int b = blockIdx.x, t = threadIdx.x;
    int add = bsum[b];
    int base = b * SCAN_CHUNK + t * 4;
    for (int i = 0; i < 4; ++i)
        if (base + i < n) fill[base + i] += add;
}

__global__ void k_fill(const int* __restrict__ src, const int* __restrict__ dst,
                       int* fill, int* __restrict__ ssrc, int E) {
    int e = blockIdx.x * blockDim.x + threadIdx.x;
    if (e < E) {
        int d = dst[e];
        int pos = atomicAdd(&fill[d], 1);
        ssrc[pos] = src[e];
    }
}

// ===================== W1 -> bf16 B-fragment swizzle =======================
// frag (kt,nt), lane l, j: W1s[((kt*8+nt)*64+l)*8+j] = bf16(W1[kt*32+(l>>4)*8+j][nt*16+(l&15)])
__global__ void k_prepW1(const float* __restrict__ W1, short* __restrict__ W1s) {
    int tid = blockIdx.x * blockDim.x + threadIdx.x;   // 0..4095
    int frag = tid >> 6, lane = tid & 63;
    int kt = frag >> 3, nt = frag & 7;
    int quad = lane >> 4, col = lane & 15;
    #pragma unroll
    for (int j = 0; j < 8; ++j) {
        int k = kt * 32 + quad * 8 + j;
        W1s[(size_t)tid * 8 + j] = f2bf(W1[k * DHID + nt * 16 + col]);
    }
}

// ===================== GEMM1 via MFMA: hb = bf16(x @ W1) ===================
// block: 256 thr = 4 waves, 128 rows (32 rows/wave = 2 row-tiles of 16)
__global__ __launch_bounds__(256) void k_gemm1_mfma(const float* __restrict__ x,
                                                    const short* __restrict__ W1s,
                                                    short* __restrict__ hb, int n) {
    __shared__ short lw[32768];  // 64 KB: full swizzled W1
    {
        const uint4* g = (const uint4*)W1s;
        uint4* l = (uint4*)lw;
        for (int i = threadIdx.x; i < 4096; i += 256) l[i] = g[i];
    }
    __syncthreads();

    int wave = threadIdx.x >> 6, lane = threadIdx.x & 63;
    int quad = lane >> 4, lrow = lane & 15;
    long long rowbase = (long long)blockIdx.x * 128 + wave * 32;

    f32x4 acc[2][8];
    #pragma unroll
    for (int rt = 0; rt < 2; ++rt)
        #pragma unroll
        for (int nt = 0; nt < 8; ++nt) acc[rt][nt] = (f32x4){0.f, 0.f, 0.f, 0.f};

    const short8* lf = (const short8*)lw;

    #pragma unroll
    for (int kt = 0; kt < 8; ++kt) {
        int k0 = kt * 32 + quad * 8;
        short8 a[2];
        #pragma unroll
        for (int rt = 0; rt < 2; ++rt) {
            long long row = rowbase + rt * 16 + lrow;
            float4 v0 = {0.f,0.f,0.f,0.f}, v1 = {0.f,0.f,0.f,0.f};
            if (row < n) {
                const float* xp = x + row * DIN + k0;
                v0 = *(const float4*)xp;
                v1 = *(const float4*)(xp + 4);
            }
            short8 av;
            av[0] = f2bf(v0.x); av[1] = f2bf(v0.y); av[2] = f2bf(v0.z); av[3] = f2bf(v0.w);
            av[4] = f2bf(v1.x); av[5] = f2bf(v1.y); av[6] = f2bf(v1.z); av[7] = f2bf(v1.w);
            a[rt] = av;
        }
        #pragma unroll
        for (int nt = 0; nt < 8; ++nt) {
            short8 b = lf[(kt * 8 + nt) * 64 + lane];
            acc[0][nt] = __builtin_amdgcn_mfma_f32_16x16x32_bf16(a[0], b, acc[0][nt], 0, 0, 0);
            acc[1][nt] = __builtin_amdgcn_mfma_f32_16x16x32_bf16(a[1], b, acc[1][nt], 0, 0, 0);
        }
    }
    // C/D: col = lane&15, row = quad*4 + r
    #pragma unroll
    for (int rt = 0; rt < 2; ++rt)
        #pragma unroll
        for (int nt = 0; nt < 8; ++nt)
            #pragma unroll
            for (int r = 0; r < 4; ++r) {
                long long row = rowbase + rt * 16 + quad * 4 + r;
                if (row < n) hb[row * DHID + nt * 16 + lrow] = f2bf(acc[rt][nt][r]);
            }
}

// ===================== gather layer 1 (bf16 h, fused epilogue) =============
__global__ void k_gather1(const int* __restrict__ fillend, const int* __restrict__ degi,
                          const int* __restrict__ ssrc, const float* __restrict__ dinv,
                          const unsigned int* __restrict__ hu, const float* __restrict__ b1,
                          float* __restrict__ h1, int n) {
    int node = blockIdx.x * 4 + (threadIdx.x >> 6);
    int t = threadIdx.x & 63;
    if (node >= n) return;
    int cnt = degi[node];
    int beg = fillend[node] - cnt;
    float ax = 0.f, ay = 0.f;
    for (int k = 0; k < cnt; ++k) {
        int s = ssrc[beg + k];
        float ds = dinv[s];
        unsigned int u = hu[(size_t)s * 64 + t];
        ax += ds * __uint_as_float(u << 16);
        ay += ds * __uint_as_float(u & 0xffff0000u);
    }
    float di = dinv[node];
    unsigned int us = hu[(size_t)node * 64 + t];
    float2 bb = ((const float2*)b1)[t];
    float vx = di * ax + __uint_as_float(us << 16) * di * di + bb.x;
    float vy = di * ay + __uint_as_float(us & 0xffff0000u) * di * di + bb.y;
    float2 o;
    o.x = vx > 0.f ? vx : 0.f;
    o.y = vy > 0.f ? vy : 0.f;
    ((float2*)h1)[(size_t)node * 64 + t] = o;
}

// ============================ GEMM2 (fp32) =================================
__global__ void k_gemm2(const float* __restrict__ h1, const float* __restrict__ W2,
                        float* __restrict__ h2, int n) {
    __shared__ float hs[4][DHID];
    int row0 = blockIdx.x * 4;
    int t = threadIdx.x;  // 0..63
    for (int i = t; i < 4 * DHID; i += 64) {
        int r = i / DHID, c = i % DHID;
        int row = row0 + r;
        hs[r][c] = (row < n) ? h1[(long long)row * DHID + c] : 0.0f;
    }
    __syncthreads();
    if (t < NCLS) {
        float acc0 = 0.f, acc1 = 0.f, acc2 = 0.f, acc3 = 0.f;
        #pragma unroll 8
        for (int k = 0; k < DHID; ++k) {
            float w = W2[k * NCLS + t];
            acc0 += hs[0][k] * w;
            acc1 += hs[1][k] * w;
            acc2 += hs[2][k] * w;
            acc3 += hs[3][k] * w;
        }
        float acc[4] = {acc0, acc1, acc2, acc3};
        for (int r = 0; r < 4; ++r) {
            int row = row0 + r;
            if (row < n) h2[(long long)row * NCLS + t] = acc[r];
        }
    }
}

// ===================== gather layer 2 (fused epilogue) =====================
__global__ void k_gather2(const int* __restrict__ fillend, const int* __restrict__ degi,
                          const int* __restrict__ ssrc, const float* __restrict__ dinv,
                          const float* __restrict__ h2, const float* __restrict__ b2,
                          float* __restrict__ out, int n) {
    int node = blockIdx.x * 4 + (threadIdx.x >> 6);
    int t = threadIdx.x & 63;
    if (node >= n) return;
    int cnt = degi[node];
    int beg = fillend[node] - cnt;
    float acc = 0.f;
    bool act = (t < NCLS);
    for (int k = 0; k < cnt; ++k) {
        int s = ssrc[beg + k];
        float ds = dinv[s];
        if (act) acc += ds * h2[(long long)s * NCLS + t];
    }
    if (act) {
        float di = dinv[node];
        float v = di * acc + h2[(long long)node * NCLS + t] * di * di + b2[t];
        out[(long long)node * NCLS + t] = v;
    }
}

// ===========================================================================
extern "C" void kernel_launch(void* const* d_in, const int* in_sizes, int n_in,
                              void* d_out, int out_size, void* d_ws, size_t ws_size,
                              hipStream_t stream) {
    const float* x  = (const float*)d_in[0];
    const int*   ei = (const int*)d_in[1];
    const float* W1 = (const float*)d_in[2];
    const float* b1 = (const float*)d_in[3];
    const float* W2 = (const float*)d_in[4];
    const float* b2 = (const float*)d_in[5];

    const int n = in_sizes[0] / DIN;   // 100000
    const int E = in_sizes[1] / 2;     // 1600000
    const int* src = ei;
    const int* dst = ei + E;
    float* out = (float*)d_out;

    // workspace layout (all offsets 16B-aligned) ~103 MB
    char* w = (char*)d_ws;
    int*   degi = (int*)w;                     w += (size_t)n * 4;
    int*   fill = (int*)w;                     w += (size_t)n * 4;
    int*   bsum = (int*)w;                     w += 128 * 4;
    float* dinv = (float*)w;                   w += (size_t)n * 4;
    int*   ssrc = (int*)w;                     w += (size_t)E * 4;
    short* W1s  = (short*)w;                   w += (size_t)32768 * 2;     // 64 KB
    short* hb   = (short*)w;                   w += (size_t)n * DHID * 2;  // bf16 x@W1
    float* h1   = (float*)w;                   w += (size_t)n * DHID * 4;
    float* h2   = (float*)w;                   w += (size_t)n * NCLS * 4;

    const int B = (n + SCAN_CHUNK - 1) / SCAN_CHUNK;  // 98

    // 1. CSR build + norms (+ W1 swizzle, overlappable)
    hipMemsetAsync(degi, 0, (size_t)n * sizeof(int), stream);
    k_prepW1<<<16, 256, 0, stream>>>(W1, W1s);
    k_count<<<(E + 255) / 256, 256, 0, stream>>>(dst, degi, E);
    k_dinv<<<(n + 255) / 256, 256, 0, stream>>>(degi, dinv, n);
    k_scan1<<<B, 256, 0, stream>>>(degi, fill, bsum, n);
    k_scan2<<<1, 64, 0, stream>>>(bsum, B);
    k_scan3<<<B, 256, 0, stream>>>(fill, bsum, n);
    k_fill<<<(E + 255) / 256, 256, 0, stream>>>(src, dst, fill, ssrc, E);

    // 2. layer 1: MFMA transform then gather-aggregate (fused bias+self+relu)
    k_gemm1_mfma<<<(n + 127) / 128, 256, 0, stream>>>(x, W1s, hb, n);
    k_gather1<<<(n + 3) / 4, 256, 0, stream>>>(fill, degi, ssrc, dinv,
                                               (const unsigned int*)hb, b1, h1, n);

    // 3. layer 2: transform then gather-aggregate (fused bias+self)
    k_gemm2<<<(n + 3) / 4, 64, 0, stream>>>(h1, W2, h2, n);
    k_gather2<<<(n + 3) / 4, 256, 0, stream>>>(fill, degi, ssrc, dinv, h2, b2, out, n);
}

// Round 4
// 545.070 us; speedup vs baseline: 2.7242x; 1.3564x over previous
//
#include <hip/hip_runtime.h>
#include <hip/hip_bf16.h>

#define DIN 256
#define DHID 128
#define NCLS 47
#define SCAN_CHUNK 1024

typedef __attribute__((ext_vector_type(8))) short short8;   // 8 bf16 (4 VGPRs)
typedef __attribute__((ext_vector_type(4))) float f32x4;

__device__ __forceinline__ short f2bf(float f) {
    __bf16 b = (__bf16)f;                 // RNE convert
    return __builtin_bit_cast(short, b);
}
__device__ __forceinline__ float bfu(unsigned int u) {   // low 16 bits = bf16
    return __uint_as_float(u << 16);
}

// ============================ CSR build ====================================
__global__ void k_count(const int* __restrict__ dst, int* degi, int E) {
    int e = blockIdx.x * blockDim.x + threadIdx.x;
    if (e < E) atomicAdd(&degi[dst[e]], 1);
}

__global__ void k_dinv(const int* __restrict__ degi, float* dinv, int n) {
    int i = blockIdx.x * blockDim.x + threadIdx.x;
    if (i < n) dinv[i] = rsqrtf((float)(degi[i] + 1));  // +1 self-loop
}

__global__ void k_scan1(const int* __restrict__ degi, int* __restrict__ fill,
                        int* __restrict__ bsum, int n) {
    __shared__ int wsum[4];
    int b = blockIdx.x, t = threadIdx.x;
    int base = b * SCAN_CHUNK + t * 4;
    int v0 = (base + 0 < n) ? degi[base + 0] : 0;
    int v1 = (base + 1 < n) ? degi[base + 1] : 0;
    int v2 = (base + 2 < n) ? degi[base + 2] : 0;
    int v3 = (base + 3 < n) ? degi[base + 3] : 0;
    int s = v0 + v1 + v2 + v3;
    int lane = t & 63, w = t >> 6;
    int sc = s;
    for (int off = 1; off < 64; off <<= 1) {
        int u = __shfl_up(sc, off, 64);
        if (lane >= off) sc += u;
    }
    if (lane == 63) wsum[w] = sc;
    __syncthreads();
    int wadd = 0;
    for (int i = 0; i < w; ++i) wadd += wsum[i];
    int excl = wadd + sc - s;
    if (base + 0 < n) fill[base + 0] = excl;
    if (base + 1 < n) fill[base + 1] = excl + v0;
    if (base + 2 < n) fill[base + 2] = excl + v0 + v1;
    if (base + 3 < n) fill[base + 3] = excl + v0 + v1 + v2;
    if (t == 255) bsum[b] = excl + s;
}

__global__ void k_scan2(int* bsum, int B) {
    if (blockIdx.x == 0 && threadIdx.x == 0) {
        int run = 0;
        for (int i = 0; i < B; ++i) { int v = bsum[i]; bsum[i] = run; run += v; }
    }
}

__global__ void k_scan3(int* fill, const int* __restrict__ bsum, int n) {
    int b = blockIdx.x, t = threadIdx.x;
    int add = bsum[b];
    int base = b * SCAN_CHUNK + t * 4;
    for (int i = 0; i < 4; ++i)
        if (base + i < n) fill[base + i] += add;
}

__global__ void k_fill(const int* __restrict__ src, const int* __restrict__ dst,
                       int* fill, int* __restrict__ ssrc, int E) {
    int e = blockIdx.x * blockDim.x + threadIdx.x;
    if (e < E) {
        int d = dst[e];
        int pos = atomicAdd(&fill[d], 1);
        ssrc[pos] = src[e];
    }
}

// ===================== W1 -> bf16 B-fragment swizzle =======================
__global__ void k_prepW1(const float* __restrict__ W1, short* __restrict__ W1s) {
    int tid = blockIdx.x * blockDim.x + threadIdx.x;   // 0..4095
    int frag = tid >> 6, lane = tid & 63;
    int kt = frag >> 3, nt = frag & 7;
    int quad = lane >> 4, col = lane & 15;
    #pragma unroll
    for (int j = 0; j < 8; ++j) {
        int k = kt * 32 + quad * 8 + j;
        W1s[(size_t)tid * 8 + j] = f2bf(W1[k * DHID + nt * 16 + col]);
    }
}

// ===================== W2 -> bf16 B-fragment swizzle (pad N to 64) =========
__global__ void k_prepW2(const float* __restrict__ W2, short* __restrict__ W2s) {
    int tid = blockIdx.x * blockDim.x + threadIdx.x;   // 0..1023
    int frag = tid >> 6, lane = tid & 63;
    int kt = frag >> 2, nt = frag & 3;
    int quad = lane >> 4, col = lane & 15;
    int c = nt * 16 + col;
    #pragma unroll
    for (int j = 0; j < 8; ++j) {
        int k = kt * 32 + quad * 8 + j;
        float v = (c < NCLS) ? W2[k * NCLS + c] : 0.0f;
        W2s[(size_t)tid * 8 + j] = f2bf(v);
    }
}

// ===================== GEMM1 via MFMA: hb = bf16(x @ W1) ===================
__global__ __launch_bounds__(256) void k_gemm1_mfma(const float* __restrict__ x,
                                                    const short* __restrict__ W1s,
                                                    short* __restrict__ hb, int n) {
    __shared__ short lw[32768];  // 64 KB: full swizzled W1
    {
        const uint4* g = (const uint4*)W1s;
        uint4* l = (uint4*)lw;
        for (int i = threadIdx.x; i < 4096; i += 256) l[i] = g[i];
    }
    __syncthreads();

    int wave = threadIdx.x >> 6, lane = threadIdx.x & 63;
    int quad = lane >> 4, lrow = lane & 15;
    long long rowbase = (long long)blockIdx.x * 128 + wave * 32;

    f32x4 acc[2][8];
    #pragma unroll
    for (int rt = 0; rt < 2; ++rt)
        #pragma unroll
        for (int nt = 0; nt < 8; ++nt) acc[rt][nt] = (f32x4){0.f, 0.f, 0.f, 0.f};

    const short8* lf = (const short8*)lw;

    #pragma unroll
    for (int kt = 0; kt < 8; ++kt) {
        int k0 = kt * 32 + quad * 8;
        short8 a[2];
        #pragma unroll
        for (int rt = 0; rt < 2; ++rt) {
            long long row = rowbase + rt * 16 + lrow;
            float4 v0 = {0.f,0.f,0.f,0.f}, v1 = {0.f,0.f,0.f,0.f};
            if (row < n) {
                const float* xp = x + row * DIN + k0;
                v0 = *(const float4*)xp;
                v1 = *(const float4*)(xp + 4);
            }
            short8 av;
            av[0] = f2bf(v0.x); av[1] = f2bf(v0.y); av[2] = f2bf(v0.z); av[3] = f2bf(v0.w);
            av[4] = f2bf(v1.x); av[5] = f2bf(v1.y); av[6] = f2bf(v1.z); av[7] = f2bf(v1.w);
            a[rt] = av;
        }
        #pragma unroll
        for (int nt = 0; nt < 8; ++nt) {
            short8 b = lf[(kt * 8 + nt) * 64 + lane];
            acc[0][nt] = __builtin_amdgcn_mfma_f32_16x16x32_bf16(a[0], b, acc[0][nt], 0, 0, 0);
            acc[1][nt] = __builtin_amdgcn_mfma_f32_16x16x32_bf16(a[1], b, acc[1][nt], 0, 0, 0);
        }
    }
    #pragma unroll
    for (int rt = 0; rt < 2; ++rt)
        #pragma unroll
        for (int nt = 0; nt < 8; ++nt)
            #pragma unroll
            for (int r = 0; r < 4; ++r) {
                long long row = rowbase + rt * 16 + quad * 4 + r;
                if (row < n) hb[row * DHID + nt * 16 + lrow] = f2bf(acc[rt][nt][r]);
            }
}

// ===== gather layer 1 (bf16 h in, bf16 h1 out, 4x unroll, fused epilogue) ==
__global__ void k_gather1(const int* __restrict__ fillend, const int* __restrict__ degi,
                          const int* __restrict__ ssrc, const float* __restrict__ dinv,
                          const unsigned int* __restrict__ hu, const float* __restrict__ b1,
                          unsigned int* __restrict__ h1u, int n) {
    int node = blockIdx.x * 4 + (threadIdx.x >> 6);
    int t = threadIdx.x & 63;
    if (node >= n) return;
    int cnt = degi[node];
    int beg = fillend[node] - cnt;
    float ax = 0.f, ay = 0.f;
    int k = 0;
    for (; k + 4 <= cnt; k += 4) {
        int s0 = ssrc[beg + k + 0], s1 = ssrc[beg + k + 1];
        int s2 = ssrc[beg + k + 2], s3 = ssrc[beg + k + 3];
        float d0 = dinv[s0], d1 = dinv[s1], d2 = dinv[s2], d3 = dinv[s3];
        unsigned int u0 = hu[(size_t)s0 * 64 + t];
        unsigned int u1 = hu[(size_t)s1 * 64 + t];
        unsigned int u2 = hu[(size_t)s2 * 64 + t];
        unsigned int u3 = hu[(size_t)s3 * 64 + t];
        ax += d0 * bfu(u0) + d1 * bfu(u1) + d2 * bfu(u2) + d3 * bfu(u3);
        ay += d0 * __uint_as_float(u0 & 0xffff0000u) + d1 * __uint_as_float(u1 & 0xffff0000u)
            + d2 * __uint_as_float(u2 & 0xffff0000u) + d3 * __uint_as_float(u3 & 0xffff0000u);
    }
    for (; k < cnt; ++k) {
        int s = ssrc[beg + k];
        float ds = dinv[s];
        unsigned int u = hu[(size_t)s * 64 + t];
        ax += ds * bfu(u);
        ay += ds * __uint_as_float(u & 0xffff0000u);
    }
    float di = dinv[node];
    unsigned int us = hu[(size_t)node * 64 + t];
    float2 bb = ((const float2*)b1)[t];
    float vx = di * ax + bfu(us) * di * di + bb.x;
    float vy = di * ay + __uint_as_float(us & 0xffff0000u) * di * di + bb.y;
    vx = vx > 0.f ? vx : 0.f;
    vy = vy > 0.f ? vy : 0.f;
    unsigned int o = (unsigned int)(unsigned short)f2bf(vx)
                   | ((unsigned int)(unsigned short)f2bf(vy) << 16);
    h1u[(size_t)node * 64 + t] = o;
}

// ========== GEMM2 via MFMA: h2b[n,64] = bf16(h1b[n,128] @ W2pad) ===========
__global__ __launch_bounds__(256) void k_gemm2_mfma(const short* __restrict__ h1b,
                                                    const short* __restrict__ W2s,
                                                    short* __restrict__ h2b, int n) {
    __shared__ short lw[8192];  // 16 KB: swizzled padded W2
    {
        const uint4* g = (const uint4*)W2s;
        uint4* l = (uint4*)lw;
        for (int i = threadIdx.x; i < 1024; i += 256) l[i] = g[i];
    }
    __syncthreads();

    int wave = threadIdx.x >> 6, lane = threadIdx.x & 63;
    int quad = lane >> 4, lrow = lane & 15;
    long long row0 = (long long)blockIdx.x * 64 + wave * 16;

    f32x4 acc[4];
    #pragma unroll
    for (int nt = 0; nt < 4; ++nt) acc[nt] = (f32x4){0.f, 0.f, 0.f, 0.f};

    const short8* lf = (const short8*)lw;

    #pragma unroll
    for (int kt = 0; kt < 4; ++kt) {
        long long row = row0 + lrow;
        short8 a = (short8){0,0,0,0,0,0,0,0};
        if (row < n) a = *(const short8*)(h1b + row * DHID + kt * 32 + quad * 8);
        #pragma unroll
        for (int nt = 0; nt < 4; ++nt)
            acc[nt] = __builtin_amdgcn_mfma_f32_16x16x32_bf16(a, lf[(kt * 4 + nt) * 64 + lane], acc[nt], 0, 0, 0);
    }
    #pragma unroll
    for (int nt = 0; nt < 4; ++nt)
        #pragma unroll
        for (int r = 0; r < 4; ++r) {
            long long row = row0 + quad * 4 + r;
            if (row < n) h2b[row * 64 + nt * 16 + lrow] = f2bf(acc[nt][r]);
        }
}

// ===== gather layer 2 (bf16 padded h2, 4x unroll, fused epilogue) ==========
__global__ void k_gather2(const int* __restrict__ fillend, const int* __restrict__ degi,
                          const int* __restrict__ ssrc, const float* __restrict__ dinv,
                          const unsigned short* __restrict__ h2b, const float* __restrict__ b2,
                          float* __restrict__ out, int n) {
    int node = blockIdx.x * 4 + (threadIdx.x >> 6);
    int t = threadIdx.x & 63;
    if (node >= n) return;
    int cnt = degi[node];
    int beg = fillend[node] - cnt;
    float acc = 0.f;
    int k = 0;
    for (; k + 4 <= cnt; k += 4) {
        int s0 = ssrc[beg + k + 0], s1 = ssrc[beg + k + 1];
        int s2 = ssrc[beg + k + 2], s3 = ssrc[beg + k + 3];
        float d0 = dinv[s0], d1 = dinv[s1], d2 = dinv[s2], d3 = dinv[s3];
        unsigned int u0 = h2b[(size_t)s0 * 64 + t];
        unsigned int u1 = h2b[(size_t)s1 * 64 + t];
        unsigned int u2 = h2b[(size_t)s2 * 64 + t];
        unsigned int u3 = h2b[(size_t)s3 * 64 + t];
        acc += d0 * bfu(u0) + d1 * bfu(u1) + d2 * bfu(u2) + d3 * bfu(u3);
    }
    for (; k < cnt; ++k) {
        int s = ssrc[beg + k];
        acc += dinv[s] * bfu((unsigned int)h2b[(size_t)s * 64 + t]);
    }
    if (t < NCLS) {
        float di = dinv[node];
        float self = bfu((unsigned int)h2b[(size_t)node * 64 + t]);
        out[(size_t)node * NCLS + t] = di * acc + self * di * di + b2[t];
    }
}

// ===========================================================================
extern "C" void kernel_launch(void* const* d_in, const int* in_sizes, int n_in,
                              void* d_out, int out_size, void* d_ws, size_t ws_size,
                              hipStream_t stream) {
    const float* x  = (const float*)d_in[0];
    const int*   ei = (const int*)d_in[1];
    const float* W1 = (const float*)d_in[2];
    const float* b1 = (const float*)d_in[3];
    const float* W2 = (const float*)d_in[4];
    const float* b2 = (const float*)d_in[5];

    const int n = in_sizes[0] / DIN;   // 100000
    const int E = in_sizes[1] / 2;     // 1600000
    const int* src = ei;
    const int* dst = ei + E;
    float* out = (float*)d_out;

    // workspace layout (~72 MB)
    char* w = (char*)d_ws;
    int*   degi = (int*)w;                     w += (size_t)n * 4;
    int*   fill = (int*)w;                     w += (size_t)n * 4;
    int*   bsum = (int*)w;                     w += 128 * 4;
    float* dinv = (float*)w;                   w += (size_t)n * 4;
    int*   ssrc = (int*)w;                     w += (size_t)E * 4;
    short* W1s  = (short*)w;                   w += (size_t)32768 * 2;     // 64 KB
    short* W2s  = (short*)w;                   w += (size_t)8192 * 2;      // 16 KB
    short* hb   = (short*)w;                   w += (size_t)n * DHID * 2;  // bf16 x@W1
    short* h1b  = (short*)w;                   w += (size_t)n * DHID * 2;  // bf16 relu layer1
    short* h2b  = (short*)w;                   w += (size_t)n * 64 * 2;    // bf16 h1@W2, N-pad 64

    const int B = (n + SCAN_CHUNK - 1) / SCAN_CHUNK;  // 98

    // 1. CSR build + norms + weight swizzles
    hipMemsetAsync(degi, 0, (size_t)n * sizeof(int), stream);
    k_prepW1<<<16, 256, 0, stream>>>(W1, W1s);
    k_prepW2<<<4, 256, 0, stream>>>(W2, W2s);
    k_count<<<(E + 255) / 256, 256, 0, stream>>>(dst, degi, E);
    k_dinv<<<(n + 255) / 256, 256, 0, stream>>>(degi, dinv, n);
    k_scan1<<<B, 256, 0, stream>>>(degi, fill, bsum, n);
    k_scan2<<<1, 64, 0, stream>>>(bsum, B);
    k_scan3<<<B, 256, 0, stream>>>(fill, bsum, n);
    k_fill<<<(E + 255) / 256, 256, 0, stream>>>(src, dst, fill, ssrc, E);

    // 2. layer 1: MFMA transform -> gather (fused bias+self+relu, bf16 out)
    k_gemm1_mfma<<<(n + 127) / 128, 256, 0, stream>>>(x, W1s, hb, n);
    k_gather1<<<(n + 3) / 4, 256, 0, stream>>>(fill, degi, ssrc, dinv,
                                               (const unsigned int*)hb, b1,
                                               (unsigned int*)h1b, n);

    // 3. layer 2: MFMA transform -> gather (fused bias+self)
    k_gemm2_mfma<<<(n + 63) / 64, 256, 0, stream>>>(h1b, W2s, h2b, n);
    k_gather2<<<(n + 3) / 4, 256, 0, stream>>>(fill, degi, ssrc, dinv,
                                               (const unsigned short*)h2b, b2, out, n);
}